// Round 3
// baseline (7719.628 us; speedup 1.0000x reference)
//
#include <hip/hip_runtime.h>
#include <stdint.h>

// ---------------------------------------------------------------------------
// Fused spiking-MLP forward: 20 timesteps, B=16384, 784 -> 400 -> 10.
//
// RNG (verified round 2, absmax 0.0): jax threefry PARTITIONABLE semantics:
//   key_t = TF((0,42),(0,t));  element e: bits = x0^x1 of TF(key_t,(0,e));
//   u = bitcast((bits>>9)|0x3f800000)-1;  xi = (x > u).
// fp64 membranes (knife-edge mem>0.5 thresholds; fp32 would flip spikes).
//
// Round-3 structure change (round 2 was LDS-issue-bound, 5.3/6.2 ms in the
// LDS pipe): 8 samples/WAVE (was 4) -> weight ds_read traffic per add halves.
//   grid 512 x 256thr; block owns 32 samples (rows g*32..+31), wave sg owns
//   q = 8sg..8sg+7. Thread covers neurons j = lane + 64k, k<7 (pad to 448).
//   Weight tile [dt][j] f32, TD=16, DOUBLE-BUFFERED (1 barrier/tile),
//   k-stride-64 reads arranged for ds_read2_b32 fusion.
//   __launch_bounds__(256,2): 256-VGPR cap so mem1[8][7] stays in VGPRs.
// ---------------------------------------------------------------------------

#define BSZ    16384
#define INDIM  784
#define HID    400
#define ODIM   10
#define TSTEPS 20

#define TD   16           // d-tile size
#define NT   49           // 784/16 tiles
#define WTJ  448          // padded neuron rows in LDS tile
#define SPB  32           // samples per block
#define SPWV 8            // samples per wave
#define XIW  26           // xi words per sample (784 bits -> 25, +1 pad)
#define SPW  14           // spike words per sample (448 bits)

__device__ __forceinline__ void tfr(uint32_t& x0, uint32_t& x1, int r) {
  x0 += x1;
  x1 = (x1 << r) | (x1 >> (32 - r));
  x1 ^= x0;
}

__device__ __forceinline__ uint2 tf2x32(uint32_t k0, uint32_t k1,
                                        uint32_t c0, uint32_t c1) {
  uint32_t k2 = k0 ^ k1 ^ 0x1BD11BDAu;
  uint32_t x0 = c0 + k0, x1 = c1 + k1;
  tfr(x0,x1,13); tfr(x0,x1,15); tfr(x0,x1,26); tfr(x0,x1,6);
  x0 += k1; x1 += k2 + 1u;
  tfr(x0,x1,17); tfr(x0,x1,29); tfr(x0,x1,16); tfr(x0,x1,24);
  x0 += k2; x1 += k0 + 2u;
  tfr(x0,x1,13); tfr(x0,x1,15); tfr(x0,x1,26); tfr(x0,x1,6);
  x0 += k0; x1 += k1 + 3u;
  tfr(x0,x1,17); tfr(x0,x1,29); tfr(x0,x1,16); tfr(x0,x1,24);
  x0 += k1; x1 += k2 + 4u;
  tfr(x0,x1,13); tfr(x0,x1,15); tfr(x0,x1,26); tfr(x0,x1,6);
  x0 += k2; x1 += k0 + 5u;
  return make_uint2(x0, x1);
}

__device__ __forceinline__ float bits_to_unif(uint32_t b) {
  return __uint_as_float((b >> 9) | 0x3f800000u) - 1.0f;
}

__global__ __launch_bounds__(256, 2)
void snn_fused(const float* __restrict__ x,  const float* __restrict__ W1,
               const float* __restrict__ b1, const float* __restrict__ W2,
               const float* __restrict__ b2, float* __restrict__ out) {
  __shared__ float    wt[2][TD * WTJ];   // 2 x 28672 B, layout [dt][j]
  __shared__ uint32_t xib[SPB][XIW];     // 3328 B
  __shared__ uint32_t spk[SPB][SPW];     // 1792 B

  const int tid  = threadIdx.x;
  const int g    = blockIdx.x;           // 0..511
  const int sg   = tid >> 6;             // wave id
  const int lane = tid & 63;             // neuron-thread index

  // persistent per-thread layer-1 state: mem1[s][k] for samples 8sg+s,
  // neurons j = lane + 64k (j>=400 are zero-padded dummies)
  double   mem1[SPWV][7];
  uint32_t spv[SPWV];                    // prev-step spike bits (bit k)
#pragma unroll
  for (int s = 0; s < SPWV; ++s) {
    spv[s] = 0u;
#pragma unroll
    for (int k = 0; k < 7; ++k) mem1[s][k] = 0.0;
  }

  // b1 cached in registers (f64), zero for pad neurons
  double b1r[7];
#pragma unroll
  for (int k = 0; k < 7; ++k) {
    const int j = lane + 64 * k;
    b1r[k] = (j < HID) ? (double)b1[j] : 0.0;
  }

  // layer-2 ownership: 320 (sample,out) pairs over 256 threads.
  // pair pa = tid (all threads), pair pb = 256+tid (tid<64 only).
  const int lsa = tid / ODIM,          loa = tid - lsa * ODIM;
  const int pb  = 256 + tid;
  const int lsb = pb / ODIM,           lob = pb - lsb * ODIM;
  const bool hasb = (tid < 64);
  double m2a = 0.0, m2b = 0.0;
  int    s2a = 0, s2b = 0, c2a = 0, c2b = 0;
  const double b2a = (double)b2[loa];
  const double b2b = hasb ? (double)b2[lob] : 0.0;

  // ---- staging: W1[0:448][d0:d0+16] -> wt[nb][dt][j], zero-pad j>=400 ----
  auto stage = [&](int d0, int nb) {
#pragma unroll
    for (int half = 0; half < 2; ++half) {
      const int jj = tid + 256 * half;
      if (jj < WTJ) {
        float v[TD];
        if (jj < HID) {
          const float4* src = (const float4*)(W1 + jj * INDIM + d0);
          float4 a = src[0], b = src[1], c = src[2], dd = src[3];
          v[0]=a.x; v[1]=a.y; v[2]=a.z; v[3]=a.w;
          v[4]=b.x; v[5]=b.y; v[6]=b.z; v[7]=b.w;
          v[8]=c.x; v[9]=c.y; v[10]=c.z; v[11]=c.w;
          v[12]=dd.x; v[13]=dd.y; v[14]=dd.z; v[15]=dd.w;
        } else {
#pragma unroll
          for (int q = 0; q < TD; ++q) v[q] = 0.0f;
        }
#pragma unroll
        for (int dt = 0; dt < TD; ++dt) wt[nb][dt * WTJ + jj] = v[dt];
      }
    }
  };

  stage(0, 0);   // tile tc=0 -> buffer 0

  for (int t = 0; t < TSTEPS; ++t) {
    // ---- step key: foldlike split -> key_t = TF((0,42), (0,t)) ----
    const uint2 kt = tf2x32(0u, 42u, 0u, (uint32_t)t);

    // ---- xi generation: wave sg produces samples 8sg..8sg+7 ----
#pragma unroll
    for (int s = 0; s < SPWV; ++s) {
      const int q   = SPWV * sg + s;
      const int row = g * SPB + q;
      for (int c = 0; c < 13; ++c) {
        const int d = c * 64 + lane;
        int xb = 0;
        if (d < INDIM) {
          const uint32_t e = (uint32_t)row * (uint32_t)INDIM + (uint32_t)d;
          uint2 r = tf2x32(kt.x, kt.y, 0u, e);
          xb = x[row * INDIM + d] > bits_to_unif(r.x ^ r.y);
        }
        unsigned long long m = __ballot(xb);
        if (lane == 0) {
          xib[q][2*c]     = (uint32_t)m;
          xib[q][2*c + 1] = (uint32_t)(m >> 32);
        }
      }
    }

    // ---- decay + reset (ref: mem*0.2*(1-spike)) ----
#pragma unroll
    for (int s = 0; s < SPWV; ++s)
#pragma unroll
      for (int k = 0; k < 7; ++k)
        mem1[s][k] = ((spv[s] >> k) & 1u) ? 0.0 : mem1[s][k] * 0.2;

    // ---- layer 1: 49 double-buffered d-tiles ----
    for (int td = 0; td < NT; ++td) {
      const int tc = t * NT + td;            // global tile counter
      const int nb = tc & 1;
      __syncthreads();   // stage(tc) visible; xib ready; old buffer free
      if (td < NT - 1)        stage((td + 1) * TD, nb ^ 1);
      else if (t < TSTEPS - 1) stage(0,            nb ^ 1);

      // xi bits for this tile (wave-uniform per sample)
      const int wi = td >> 1;
      const int sh = (td & 1) * 16;
      uint32_t xw[SPWV];
#pragma unroll
      for (int s = 0; s < SPWV; ++s)
        xw[s] = (xib[SPWV*sg + s][wi] >> sh) & 0xFFFFu;

      const float* wbase = &wt[nb][lane];
#pragma unroll 4
      for (int dt = 0; dt < TD; ++dt) {
        const float* wr = wbase + dt * WTJ;
        double wd[7];
#pragma unroll
        for (int k = 0; k < 7; ++k) wd[k] = (double)wr[64 * k];
#pragma unroll
        for (int s = 0; s < SPWV; ++s) {
          // bit is wave-uniform -> scalar branch skips ~50% of fp64 adds
          if (__builtin_amdgcn_readfirstlane((xw[s] >> dt) & 1u)) {
#pragma unroll
            for (int k = 0; k < 7; ++k) mem1[s][k] += wd[k];
          }
        }
      }
    }

    // ---- finalize layer 1: + b1, threshold, pack spikes ----
#pragma unroll
    for (int s = 0; s < SPWV; ++s) {
      uint32_t m = 0u;
#pragma unroll
      for (int k = 0; k < 7; ++k) {
        mem1[s][k] += b1r[k];
        if (mem1[s][k] > 0.5) m |= (1u << k);  // pad neurons never fire
      }
      spv[s] = m;
#pragma unroll
      for (int k = 0; k < 7; ++k) {
        unsigned long long bm = __ballot((m >> k) & 1u);
        if (lane == 0) {
          spk[SPWV*sg + s][2*k]     = (uint32_t)bm;
          spk[SPWV*sg + s][2*k + 1] = (uint32_t)(bm >> 32);
        }
      }
    }
    __syncthreads();                         // spikes visible

    // ---- layer 2: 320 pairs, bit-sparse fp64 dot over W2 rows ----
    {
      double a2  = s2a ? 0.0 : m2a * 0.2;
      double dot = 0.0;
      const float* w2r = W2 + loa * HID;
      for (int w = 0; w < 13; ++w) {
        uint32_t bits = spk[lsa][w];
        if (w == 12) bits &= 0xFFFFu;
        const int jb = 32 * w;
        while (bits) {
          const int bi = __ffs(bits) - 1;
          bits &= bits - 1u;
          dot += (double)w2r[jb + bi];
        }
      }
      m2a = (a2 + dot) + b2a;
      s2a = (m2a > 0.5) ? 1 : 0;
      c2a += s2a;
    }
    if (hasb) {
      double a2  = s2b ? 0.0 : m2b * 0.2;
      double dot = 0.0;
      const float* w2r = W2 + lob * HID;
      for (int w = 0; w < 13; ++w) {
        uint32_t bits = spk[lsb][w];
        if (w == 12) bits &= 0xFFFFu;
        const int jb = 32 * w;
        while (bits) {
          const int bi = __ffs(bits) - 1;
          bits &= bits - 1u;
          dot += (double)w2r[jb + bi];
        }
      }
      m2b = (a2 + dot) + b2b;
      s2b = (m2b > 0.5) ? 1 : 0;
      c2b += s2b;
    }
  }

  // ---- output: h2_sum / 20 ----
  out[(g * SPB + lsa) * ODIM + loa] = (float)((double)c2a / 20.0);
  if (hasb)
    out[(g * SPB + lsb) * ODIM + lob] = (float)((double)c2b / 20.0);
}

extern "C" void kernel_launch(void* const* d_in, const int* in_sizes, int n_in,
                              void* d_out, int out_size, void* d_ws, size_t ws_size,
                              hipStream_t stream) {
  const float* x  = (const float*)d_in[0];
  const float* W1 = (const float*)d_in[1];
  const float* b1 = (const float*)d_in[2];
  const float* W2 = (const float*)d_in[3];
  const float* b2 = (const float*)d_in[4];
  // d_in[5] = time_window (int, ==20) — compile-time constant here.
  float* out = (float*)d_out;
  hipLaunchKernelGGL(snn_fused, dim3(512), dim3(256), 0, stream,
                     x, W1, b1, W2, b2, out);
}